// Round 2
// baseline (347.260 us; speedup 1.0000x reference)
//
#include <hip/hip_runtime.h>
#include <math.h>

// PHM adapter: down (768->192, n=4 rank-1 kron) -> gelu_new -> up (192->768).
// Round 7b: NO LDS ROUND-TRIP (compile fix: nontemporal store needs a native
// ext_vector_type pointer, not HIP's float4 class). Round 6's per-wave LDS
// scratch was a pure pass-through: the compute consumes exactly
// x[pair*1536 + 12*lane .. +12) (a*192+12*r == 12*lane), a perfect per-lane
// partition of contiguous memory. So each lane loads its 3 float4 slices per
// token DIRECTLY from global and stores results directly back -- no
// ds_write/ds_read chain, no lgkmcnt serialization, LDS shrinks
// 31.5KB -> ~11.5KB (weights/biases only). Added: 1-deep explicit prefetch
// of the next pair's 6 float4 (loads in flight across the whole compute
// body), and nontemporal output stores so the 100MB write stream doesn't
// evict x from Infinity Cache. __launch_bounds__(256,4) pins 128-VGPR cap.

#define SQ2PI 0.79788456080286535588f

typedef float vfloat4 __attribute__((ext_vector_type(4)));

template<int CTRL>
__device__ __forceinline__ float ror_add(float v) {
    // v + rotate_within_16(v, CTRL)  (DPP row_ror — VALU pipe, no DS traffic)
    int s = __builtin_amdgcn_update_dpp(0, __float_as_int(v), CTRL, 0xF, 0xF, true);
    return v + __int_as_float(s);
}
__device__ __forceinline__ float reduce16(float v) {
    v = ror_add<0x121>(v);   // row_ror:1
    v = ror_add<0x122>(v);   // row_ror:2
    v = ror_add<0x124>(v);   // row_ror:4
    v = ror_add<0x128>(v);   // row_ror:8
    return v;                // every lane: sum over its 16-lane row
}

__device__ __forceinline__ void nt_store4(float* p, const float4& v) {
    vfloat4 nv;
    nv.x = v.x; nv.y = v.y; nv.z = v.z; nv.w = v.w;
    __builtin_nontemporal_store(nv, (vfloat4*)p);
}

__global__ __launch_bounds__(256, 4)
void phm_fused(const float* __restrict__ x,
               const float* __restrict__ rule_d,
               const float* __restrict__ Wl_d,
               const float* __restrict__ Wr_d,
               const float* __restrict__ bias_d,
               const float* __restrict__ rule_u,
               const float* __restrict__ Wl_u,
               const float* __restrict__ Wr_u,
               const float* __restrict__ bias_u,
               float* __restrict__ out,
               int n_tokens)
{
    __shared__ __attribute__((aligned(16))) float sLd[768];    // W_left_d  [i][p]  i*192+p
    __shared__ __attribute__((aligned(16))) float sRu[768];    // W_right_u [i][q2] i*192+q2
    __shared__ __attribute__((aligned(16))) float sBu[768];    // bias_u
    __shared__ __attribute__((aligned(16))) float sLu[192];    // W_left_u  [i][q]  i*48+q
    __shared__ float sRuleD[64];                               // [i][a'][c] i*16+a'*4+c
    __shared__ float sRuleU[64];

    const int tid = threadIdx.x;
    for (int i = tid; i < 768; i += 256) sLd[i] = Wl_d[i];
    for (int i = tid; i < 768; i += 256) sRu[i] = Wr_u[i];
    for (int i = tid; i < 768; i += 256) sBu[i] = bias_u[i];
    if (tid < 192)      sLu[tid]        = Wl_u[tid];
    if (tid < 64)       sRuleD[tid]     = rule_d[tid];
    else if (tid < 128) sRuleU[tid-64]  = rule_u[tid-64];

    const int lane = tid & 63;
    const int wave = tid >> 6;
    const int a    = lane >> 4;   // kron block 0..3 (also dest c for this lane)
    const int r    = lane & 15;   // slot within block
    const int off  = 12 * lane;   // this lane's contiguous slice within a token

    // ---- small persistent registers (15 floats) ----
    float bd[3];                   // bias_d at o = a*48 + 3r + w
    float rdw[4][3];               // W_right_d[i][3r+w]
    #pragma unroll
    for (int w = 0; w < 3; ++w) bd[w] = bias_d[a*48 + 3*r + w];
    #pragma unroll
    for (int i = 0; i < 4; ++i)
        #pragma unroll
        for (int w = 0; w < 3; ++w) rdw[i][w] = Wr_d[i*48 + 3*r + w];

    __syncthreads();   // the ONLY block barrier: weights staged

    const int wid     = blockIdx.x * 4 + wave;
    const int n_waves = gridDim.x * 4;
    const int n_pairs = n_tokens >> 1;

    // ---- prologue: load first pair directly into registers ----
    float4 A0[3], A1[3];
    {
        const int pr0 = (wid < n_pairs) ? wid : 0;
        const float* xp = x + (size_t)pr0 * 1536 + off;
        #pragma unroll
        for (int u = 0; u < 3; ++u) {
            A0[u] = *(const float4*)(xp + 4*u);
            A1[u] = *(const float4*)(xp + 768 + 4*u);
        }
    }

    for (int pr = wid; pr < n_pairs; pr += n_waves) {
        // ---- prefetch next pair (clamped; last iter harmlessly reloads) ----
        const int nx = pr + n_waves;
        const float* np = x + (size_t)(nx < n_pairs ? nx : pr) * 1536 + off;
        float4 B0[3], B1[3];
        #pragma unroll
        for (int u = 0; u < 3; ++u) {
            B0[u] = *(const float4*)(np + 4*u);
            B1[u] = *(const float4*)(np + 768 + 4*u);
        }

        // ---- down dots, per-u to limit register liveness ----
        float s0[4] = {0,0,0,0}, s1[4] = {0,0,0,0};
        #pragma unroll
        for (int u = 0; u < 3; ++u) {
            const float4 xa = A0[u];
            const float4 xb = A1[u];
            #pragma unroll
            for (int i = 0; i < 4; ++i) {
                const float4 lv = *(const float4*)&sLd[i*192 + 12*r + 4*u];
                s0[i] = fmaf(xa.x, lv.x, s0[i]);  s1[i] = fmaf(xb.x, lv.x, s1[i]);
                s0[i] = fmaf(xa.y, lv.y, s0[i]);  s1[i] = fmaf(xb.y, lv.y, s1[i]);
                s0[i] = fmaf(xa.z, lv.z, s0[i]);  s1[i] = fmaf(xb.z, lv.z, s1[i]);
                s0[i] = fmaf(xa.w, lv.w, s0[i]);  s1[i] = fmaf(xb.w, lv.w, s1[i]);
            }
        }

        // ---- 16-lane DPP reduce + xor-swizzle gather + rule contraction ----
        float tD0[4], tD1[4];
        #pragma unroll
        for (int i = 0; i < 4; ++i) {
            const float rk0 = sRuleD[i*16 + (a^0)*4 + a];   // broadcast reads
            const float rk1 = sRuleD[i*16 + (a^1)*4 + a];
            const float rk2 = sRuleD[i*16 + (a^2)*4 + a];
            const float rk3 = sRuleD[i*16 + (a^3)*4 + a];
            const float h0 = reduce16(s0[i]);
            const float h1 = reduce16(s1[i]);
            float x1 = __shfl_xor(h0, 16), x2 = __shfl_xor(h0, 32), x3 = __shfl_xor(x1, 32);
            tD0[i] = fmaf(h0, rk0, fmaf(x1, rk1, fmaf(x2, rk2, x3 * rk3)));
            x1 = __shfl_xor(h1, 16); x2 = __shfl_xor(h1, 32); x3 = __shfl_xor(x1, 32);
            tD1[i] = fmaf(h1, rk0, fmaf(x1, rk1, fmaf(x2, rk2, x3 * rk3)));
        }

        // ---- z + gelu at o = a*48 + 3r + w ----
        float g0[3], g1[3];
        #pragma unroll
        for (int w = 0; w < 3; ++w) {
            float z0 = bd[w], z1 = bd[w];
            #pragma unroll
            for (int i = 0; i < 4; ++i) {
                z0 = fmaf(tD0[i], rdw[i][w], z0);
                z1 = fmaf(tD1[i], rdw[i][w], z1);
            }
            const float i0 = SQ2PI * fmaf(0.044715f*z0, z0*z0, z0);
            const float i1 = SQ2PI * fmaf(0.044715f*z1, z1*z1, z1);
            const float e0 = __expf(2.0f*i0);                // tanh(y)=1-2/(e^{2y}+1)
            const float e1 = __expf(2.0f*i1);
            g0[w] = 0.5f*z0*(1.0f + (1.0f - 2.0f/(e0 + 1.0f)));
            g1[w] = 0.5f*z1*(1.0f + (1.0f - 2.0f/(e1 + 1.0f)));
        }

        // ---- up dots + reduce + gather + rule contraction ----
        float tU0[4], tU1[4];
        #pragma unroll
        for (int i = 0; i < 4; ++i) {
            const float l0 = sLu[i*48 + 3*r + 0];
            const float l1 = sLu[i*48 + 3*r + 1];
            const float l2 = sLu[i*48 + 3*r + 2];
            const float rk0 = sRuleU[i*16 + (a^0)*4 + a];
            const float rk1 = sRuleU[i*16 + (a^1)*4 + a];
            const float rk2 = sRuleU[i*16 + (a^2)*4 + a];
            const float rk3 = sRuleU[i*16 + (a^3)*4 + a];
            float a0 = g0[0]*l0 + g0[1]*l1 + g0[2]*l2;
            float a1 = g1[0]*l0 + g1[1]*l1 + g1[2]*l2;
            const float h0 = reduce16(a0);
            const float h1 = reduce16(a1);
            float x1 = __shfl_xor(h0, 16), x2 = __shfl_xor(h0, 32), x3 = __shfl_xor(x1, 32);
            tU0[i] = fmaf(h0, rk0, fmaf(x1, rk1, fmaf(x2, rk2, x3 * rk3)));
            x1 = __shfl_xor(h1, 16); x2 = __shfl_xor(h1, 32); x3 = __shfl_xor(x1, 32);
            tU1[i] = fmaf(h1, rk0, fmaf(x1, rk1, fmaf(x2, rk2, x3 * rk3)));
        }

        // ---- outputs: direct nontemporal stores (write-only stream) ----
        float* op = out + (size_t)pr * 1536 + off;
        #pragma unroll
        for (int u = 0; u < 3; ++u) {
            const float4 bv = *(const float4*)&sBu[off + 4*u];
            float4 ov0 = bv, ov1 = bv;
            #pragma unroll
            for (int i = 0; i < 4; ++i) {
                const float4 ru = *(const float4*)&sRu[i*192 + 12*r + 4*u];
                ov0.x = fmaf(tU0[i], ru.x, ov0.x);  ov1.x = fmaf(tU1[i], ru.x, ov1.x);
                ov0.y = fmaf(tU0[i], ru.y, ov0.y);  ov1.y = fmaf(tU1[i], ru.y, ov1.y);
                ov0.z = fmaf(tU0[i], ru.z, ov0.z);  ov1.z = fmaf(tU1[i], ru.z, ov1.z);
                ov0.w = fmaf(tU0[i], ru.w, ov0.w);  ov1.w = fmaf(tU1[i], ru.w, ov1.w);
            }
            nt_store4(op + 4*u,       ov0);
            nt_store4(op + 768 + 4*u, ov1);
        }

        // ---- rotate prefetch into current ----
        #pragma unroll
        for (int u = 0; u < 3; ++u) { A0[u] = B0[u]; A1[u] = B1[u]; }
    }
}

extern "C" void kernel_launch(void* const* d_in, const int* in_sizes, int n_in,
                              void* d_out, int out_size, void* d_ws, size_t ws_size,
                              hipStream_t stream) {
    const float* x      = (const float*)d_in[0];
    const float* rule_d = (const float*)d_in[1];
    const float* Wl_d   = (const float*)d_in[2];
    const float* Wr_d   = (const float*)d_in[3];
    const float* bias_d = (const float*)d_in[4];
    const float* rule_u = (const float*)d_in[5];
    const float* Wl_u   = (const float*)d_in[6];
    const float* Wr_u   = (const float*)d_in[7];
    const float* bias_u = (const float*)d_in[8];
    float* out          = (float*)d_out;

    const int n_tokens = in_sizes[0] / 768;   // 32768

    // 1024 blocks = 4096 waves; 16384 pairs -> exactly 4 pairs/wave, balanced.
    phm_fused<<<dim3(1024), dim3(256), 0, stream>>>(
        x, rule_d, Wl_d, Wr_d, bias_d, rule_u, Wl_u, Wr_u, bias_u, out, n_tokens);
}

// Round 3
// 219.130 us; speedup vs baseline: 1.5847x; 1.5847x over previous
//
#include <hip/hip_runtime.h>
#include <math.h>

// PHM adapter: down (768->192, n=4 rank-1 kron) -> gelu_new -> up (192->768).
// Round 8: Round-7 structure (no LDS round-trip, direct per-lane global
// load/store, 1-deep prefetch, nt stores) with the __launch_bounds__ min-wave
// hint REMOVED. Round 7's (256,4) made the allocator pin VGPR=64 and spill
// wholesale: WRITE_SIZE 98->335MB (spill writes), FETCH 469MB (spill reads),
// 227us. Plain __launch_bounds__(256) lets it take ~116-140 VGPR with zero
// scratch (round-0 precedent: 116 VGPR, no spill).
// Key insight retained from round 7: the compute consumes exactly
// x[pair*1536 + 12*lane .. +12) per token (a*192+12*r == 12*lane), a perfect
// per-lane partition of contiguous memory -> no LDS staging needed at all.

#define SQ2PI 0.79788456080286535588f

typedef float vfloat4 __attribute__((ext_vector_type(4)));

template<int CTRL>
__device__ __forceinline__ float ror_add(float v) {
    // v + rotate_within_16(v, CTRL)  (DPP row_ror — VALU pipe, no DS traffic)
    int s = __builtin_amdgcn_update_dpp(0, __float_as_int(v), CTRL, 0xF, 0xF, true);
    return v + __int_as_float(s);
}
__device__ __forceinline__ float reduce16(float v) {
    v = ror_add<0x121>(v);   // row_ror:1
    v = ror_add<0x122>(v);   // row_ror:2
    v = ror_add<0x124>(v);   // row_ror:4
    v = ror_add<0x128>(v);   // row_ror:8
    return v;                // every lane: sum over its 16-lane row
}

__device__ __forceinline__ void nt_store4(float* p, const float4& v) {
    vfloat4 nv;
    nv.x = v.x; nv.y = v.y; nv.z = v.z; nv.w = v.w;
    __builtin_nontemporal_store(nv, (vfloat4*)p);
}

__global__ __launch_bounds__(256)
void phm_fused(const float* __restrict__ x,
               const float* __restrict__ rule_d,
               const float* __restrict__ Wl_d,
               const float* __restrict__ Wr_d,
               const float* __restrict__ bias_d,
               const float* __restrict__ rule_u,
               const float* __restrict__ Wl_u,
               const float* __restrict__ Wr_u,
               const float* __restrict__ bias_u,
               float* __restrict__ out,
               int n_tokens)
{
    __shared__ __attribute__((aligned(16))) float sLd[768];    // W_left_d  [i][p]  i*192+p
    __shared__ __attribute__((aligned(16))) float sRu[768];    // W_right_u [i][q2] i*192+q2
    __shared__ __attribute__((aligned(16))) float sBu[768];    // bias_u
    __shared__ __attribute__((aligned(16))) float sLu[192];    // W_left_u  [i][q]  i*48+q
    __shared__ float sRuleD[64];                               // [i][a'][c] i*16+a'*4+c
    __shared__ float sRuleU[64];

    const int tid = threadIdx.x;
    for (int i = tid; i < 768; i += 256) sLd[i] = Wl_d[i];
    for (int i = tid; i < 768; i += 256) sRu[i] = Wr_u[i];
    for (int i = tid; i < 768; i += 256) sBu[i] = bias_u[i];
    if (tid < 192)      sLu[tid]        = Wl_u[tid];
    if (tid < 64)       sRuleD[tid]     = rule_d[tid];
    else if (tid < 128) sRuleU[tid-64]  = rule_u[tid-64];

    const int lane = tid & 63;
    const int wave = tid >> 6;
    const int a    = lane >> 4;   // kron block 0..3 (also dest c for this lane)
    const int r    = lane & 15;   // slot within block
    const int off  = 12 * lane;   // this lane's contiguous slice within a token

    // ---- small persistent registers (15 floats) ----
    float bd[3];                   // bias_d at o = a*48 + 3r + w
    float rdw[4][3];               // W_right_d[i][3r+w]
    #pragma unroll
    for (int w = 0; w < 3; ++w) bd[w] = bias_d[a*48 + 3*r + w];
    #pragma unroll
    for (int i = 0; i < 4; ++i)
        #pragma unroll
        for (int w = 0; w < 3; ++w) rdw[i][w] = Wr_d[i*48 + 3*r + w];

    __syncthreads();   // the ONLY block barrier: weights staged

    const int wid     = blockIdx.x * 4 + wave;
    const int n_waves = gridDim.x * 4;
    const int n_pairs = n_tokens >> 1;

    // ---- prologue: load first pair directly into registers ----
    float4 A0[3], A1[3];
    {
        const int pr0 = (wid < n_pairs) ? wid : 0;
        const float* xp = x + (size_t)pr0 * 1536 + off;
        #pragma unroll
        for (int u = 0; u < 3; ++u) {
            A0[u] = *(const float4*)(xp + 4*u);
            A1[u] = *(const float4*)(xp + 768 + 4*u);
        }
    }

    for (int pr = wid; pr < n_pairs; pr += n_waves) {
        // ---- prefetch next pair (clamped; last iter harmlessly reloads) ----
        const int nx = pr + n_waves;
        const float* np = x + (size_t)(nx < n_pairs ? nx : pr) * 1536 + off;
        float4 B0[3], B1[3];
        #pragma unroll
        for (int u = 0; u < 3; ++u) {
            B0[u] = *(const float4*)(np + 4*u);
            B1[u] = *(const float4*)(np + 768 + 4*u);
        }

        // ---- down dots, per-u to limit register liveness ----
        float s0[4] = {0,0,0,0}, s1[4] = {0,0,0,0};
        #pragma unroll
        for (int u = 0; u < 3; ++u) {
            const float4 xa = A0[u];
            const float4 xb = A1[u];
            #pragma unroll
            for (int i = 0; i < 4; ++i) {
                const float4 lv = *(const float4*)&sLd[i*192 + 12*r + 4*u];
                s0[i] = fmaf(xa.x, lv.x, s0[i]);  s1[i] = fmaf(xb.x, lv.x, s1[i]);
                s0[i] = fmaf(xa.y, lv.y, s0[i]);  s1[i] = fmaf(xb.y, lv.y, s1[i]);
                s0[i] = fmaf(xa.z, lv.z, s0[i]);  s1[i] = fmaf(xb.z, lv.z, s1[i]);
                s0[i] = fmaf(xa.w, lv.w, s0[i]);  s1[i] = fmaf(xb.w, lv.w, s1[i]);
            }
        }

        // ---- 16-lane DPP reduce + xor-swizzle gather + rule contraction ----
        float tD0[4], tD1[4];
        #pragma unroll
        for (int i = 0; i < 4; ++i) {
            const float rk0 = sRuleD[i*16 + (a^0)*4 + a];   // broadcast reads
            const float rk1 = sRuleD[i*16 + (a^1)*4 + a];
            const float rk2 = sRuleD[i*16 + (a^2)*4 + a];
            const float rk3 = sRuleD[i*16 + (a^3)*4 + a];
            const float h0 = reduce16(s0[i]);
            const float h1 = reduce16(s1[i]);
            float x1 = __shfl_xor(h0, 16), x2 = __shfl_xor(h0, 32), x3 = __shfl_xor(x1, 32);
            tD0[i] = fmaf(h0, rk0, fmaf(x1, rk1, fmaf(x2, rk2, x3 * rk3)));
            x1 = __shfl_xor(h1, 16); x2 = __shfl_xor(h1, 32); x3 = __shfl_xor(x1, 32);
            tD1[i] = fmaf(h1, rk0, fmaf(x1, rk1, fmaf(x2, rk2, x3 * rk3)));
        }

        // ---- z + gelu at o = a*48 + 3r + w ----
        float g0[3], g1[3];
        #pragma unroll
        for (int w = 0; w < 3; ++w) {
            float z0 = bd[w], z1 = bd[w];
            #pragma unroll
            for (int i = 0; i < 4; ++i) {
                z0 = fmaf(tD0[i], rdw[i][w], z0);
                z1 = fmaf(tD1[i], rdw[i][w], z1);
            }
            const float i0 = SQ2PI * fmaf(0.044715f*z0, z0*z0, z0);
            const float i1 = SQ2PI * fmaf(0.044715f*z1, z1*z1, z1);
            const float e0 = __expf(2.0f*i0);                // tanh(y)=1-2/(e^{2y}+1)
            const float e1 = __expf(2.0f*i1);
            g0[w] = 0.5f*z0*(1.0f + (1.0f - 2.0f/(e0 + 1.0f)));
            g1[w] = 0.5f*z1*(1.0f + (1.0f - 2.0f/(e1 + 1.0f)));
        }

        // ---- up dots + reduce + gather + rule contraction ----
        float tU0[4], tU1[4];
        #pragma unroll
        for (int i = 0; i < 4; ++i) {
            const float l0 = sLu[i*48 + 3*r + 0];
            const float l1 = sLu[i*48 + 3*r + 1];
            const float l2 = sLu[i*48 + 3*r + 2];
            const float rk0 = sRuleU[i*16 + (a^0)*4 + a];
            const float rk1 = sRuleU[i*16 + (a^1)*4 + a];
            const float rk2 = sRuleU[i*16 + (a^2)*4 + a];
            const float rk3 = sRuleU[i*16 + (a^3)*4 + a];
            float a0 = g0[0]*l0 + g0[1]*l1 + g0[2]*l2;
            float a1 = g1[0]*l0 + g1[1]*l1 + g1[2]*l2;
            const float h0 = reduce16(a0);
            const float h1 = reduce16(a1);
            float x1 = __shfl_xor(h0, 16), x2 = __shfl_xor(h0, 32), x3 = __shfl_xor(x1, 32);
            tU0[i] = fmaf(h0, rk0, fmaf(x1, rk1, fmaf(x2, rk2, x3 * rk3)));
            x1 = __shfl_xor(h1, 16); x2 = __shfl_xor(h1, 32); x3 = __shfl_xor(x1, 32);
            tU1[i] = fmaf(h1, rk0, fmaf(x1, rk1, fmaf(x2, rk2, x3 * rk3)));
        }

        // ---- outputs: direct nontemporal stores (write-only stream) ----
        float* op = out + (size_t)pr * 1536 + off;
        #pragma unroll
        for (int u = 0; u < 3; ++u) {
            const float4 bv = *(const float4*)&sBu[off + 4*u];
            float4 ov0 = bv, ov1 = bv;
            #pragma unroll
            for (int i = 0; i < 4; ++i) {
                const float4 ru = *(const float4*)&sRu[i*192 + 12*r + 4*u];
                ov0.x = fmaf(tU0[i], ru.x, ov0.x);  ov1.x = fmaf(tU1[i], ru.x, ov1.x);
                ov0.y = fmaf(tU0[i], ru.y, ov0.y);  ov1.y = fmaf(tU1[i], ru.y, ov1.y);
                ov0.z = fmaf(tU0[i], ru.z, ov0.z);  ov1.z = fmaf(tU1[i], ru.z, ov1.z);
                ov0.w = fmaf(tU0[i], ru.w, ov0.w);  ov1.w = fmaf(tU1[i], ru.w, ov1.w);
            }
            nt_store4(op + 4*u,       ov0);
            nt_store4(op + 768 + 4*u, ov1);
        }

        // ---- rotate prefetch into current ----
        #pragma unroll
        for (int u = 0; u < 3; ++u) { A0[u] = B0[u]; A1[u] = B1[u]; }
    }
}

extern "C" void kernel_launch(void* const* d_in, const int* in_sizes, int n_in,
                              void* d_out, int out_size, void* d_ws, size_t ws_size,
                              hipStream_t stream) {
    const float* x      = (const float*)d_in[0];
    const float* rule_d = (const float*)d_in[1];
    const float* Wl_d   = (const float*)d_in[2];
    const float* Wr_d   = (const float*)d_in[3];
    const float* bias_d = (const float*)d_in[4];
    const float* rule_u = (const float*)d_in[5];
    const float* Wl_u   = (const float*)d_in[6];
    const float* Wr_u   = (const float*)d_in[7];
    const float* bias_u = (const float*)d_in[8];
    float* out          = (float*)d_out;

    const int n_tokens = in_sizes[0] / 768;   // 32768

    // 1024 blocks = 4096 waves; 16384 pairs -> exactly 4 pairs/wave, balanced.
    phm_fused<<<dim3(1024), dim3(256), 0, stream>>>(
        x, rule_d, Wl_d, Wr_d, bias_d, rule_u, Wl_u, Wr_u, bias_u, out, n_tokens);
}

// Round 4
// 193.993 us; speedup vs baseline: 1.7901x; 1.1296x over previous
//
#include <hip/hip_runtime.h>
#include <math.h>

// PHM adapter: down (768->192, n=4 rank-1 kron) -> gelu_new -> up (192->768).
// Round 9: COALESCED per-lane remap. Round 8 (direct per-lane, 48B-stride
// accesses) showed WRITE_SIZE 98->148MB: nt stores at 48B lane stride leave
// every 64B line covered by 3-4 different store instructions -> partial-line
// streaming writes (1.5x amplification); loads had the same strided shape.
// Fix uses the kron structure's freedom: reduce16 sums over the 16 lanes of
// a row, so ANY partition of the 192 in-block positions among the 16 lanes
// is valid; likewise tU[i] is row-broadcast so a lane may write any 12-float
// subset of its block. Remap to p = a*192 + 4*(r+16u)+j: for fixed u the 16
// lanes cover a contiguous 256B segment (fully-covered cache lines, 4 rows
// at 768B stride) -> loads AND stores fully coalesced per instruction, with
// NO LDS round-trip, 1-deep prefetch, nt stores, no block barriers in loop.
// gelu stage (o=a*48+3r+w) unchanged. No min-wave hint (round-7 lesson:
// (256,4) pins VGPR=64 and spills wholesale).

#define SQ2PI 0.79788456080286535588f

typedef float vfloat4 __attribute__((ext_vector_type(4)));

template<int CTRL>
__device__ __forceinline__ float ror_add(float v) {
    // v + rotate_within_16(v, CTRL)  (DPP row_ror — VALU pipe, no DS traffic)
    int s = __builtin_amdgcn_update_dpp(0, __float_as_int(v), CTRL, 0xF, 0xF, true);
    return v + __int_as_float(s);
}
__device__ __forceinline__ float reduce16(float v) {
    v = ror_add<0x121>(v);   // row_ror:1
    v = ror_add<0x122>(v);   // row_ror:2
    v = ror_add<0x124>(v);   // row_ror:4
    v = ror_add<0x128>(v);   // row_ror:8
    return v;                // every lane: sum over its 16-lane row
}

__device__ __forceinline__ void nt_store4(float* p, const float4& v) {
    vfloat4 nv;
    nv.x = v.x; nv.y = v.y; nv.z = v.z; nv.w = v.w;
    __builtin_nontemporal_store(nv, (vfloat4*)p);
}

__global__ __launch_bounds__(256)
void phm_fused(const float* __restrict__ x,
               const float* __restrict__ rule_d,
               const float* __restrict__ Wl_d,
               const float* __restrict__ Wr_d,
               const float* __restrict__ bias_d,
               const float* __restrict__ rule_u,
               const float* __restrict__ Wl_u,
               const float* __restrict__ Wr_u,
               const float* __restrict__ bias_u,
               float* __restrict__ out,
               int n_tokens)
{
    __shared__ __attribute__((aligned(16))) float sLd[768];    // W_left_d  [i][p]  i*192+p
    __shared__ __attribute__((aligned(16))) float sRu[768];    // W_right_u [i][q2] i*192+q2
    __shared__ __attribute__((aligned(16))) float sLu[192];    // W_left_u  [i][q]  i*48+q
    __shared__ float sRuleD[64];                               // [i][a'][c] i*16+a'*4+c
    __shared__ float sRuleU[64];

    const int tid = threadIdx.x;
    for (int i = tid; i < 768; i += 256) sLd[i] = Wl_d[i];
    for (int i = tid; i < 768; i += 256) sRu[i] = Wr_u[i];
    if (tid < 192)      sLu[tid]        = Wl_u[tid];
    if (tid < 64)       sRuleD[tid]     = rule_d[tid];
    else if (tid < 128) sRuleU[tid-64]  = rule_u[tid-64];

    const int lane = tid & 63;
    const int wave = tid >> 6;
    const int a    = lane >> 4;          // kron block 0..3 (also dest c)
    const int r    = lane & 15;          // slot within block
    const int off  = 192*a + 4*r;        // coalesced remap: +64u walks the block

    // ---- small persistent registers (27 floats) ----
    float bd[3];                   // bias_d at o = a*48 + 3r + w   (gelu stage)
    float rdw[4][3];               // W_right_d[i][3r+w]
    float4 bu[3];                  // bias_u at q2-part 4r+64u of block a
    #pragma unroll
    for (int w = 0; w < 3; ++w) bd[w] = bias_d[a*48 + 3*r + w];
    #pragma unroll
    for (int i = 0; i < 4; ++i)
        #pragma unroll
        for (int w = 0; w < 3; ++w) rdw[i][w] = Wr_d[i*48 + 3*r + w];
    #pragma unroll
    for (int u = 0; u < 3; ++u)
        bu[u] = *(const float4*)(bias_u + off + 64*u);

    __syncthreads();   // the ONLY block barrier: weights staged

    const int wid     = blockIdx.x * 4 + wave;
    const int n_waves = gridDim.x * 4;
    const int n_pairs = n_tokens >> 1;

    // ---- prologue: load first pair (coalesced: 256B/row segments) ----
    float4 A0[3], A1[3];
    {
        const int pr0 = (wid < n_pairs) ? wid : 0;
        const float* xp = x + (size_t)pr0 * 1536 + off;
        #pragma unroll
        for (int u = 0; u < 3; ++u) {
            A0[u] = *(const float4*)(xp + 64*u);
            A1[u] = *(const float4*)(xp + 768 + 64*u);
        }
    }

    for (int pr = wid; pr < n_pairs; pr += n_waves) {
        // ---- prefetch next pair (clamped; last iter harmlessly reloads) ----
        const int nx = pr + n_waves;
        const float* np = x + (size_t)(nx < n_pairs ? nx : pr) * 1536 + off;
        float4 B0[3], B1[3];
        #pragma unroll
        for (int u = 0; u < 3; ++u) {
            B0[u] = *(const float4*)(np + 64*u);
            B1[u] = *(const float4*)(np + 768 + 64*u);
        }

        // ---- down dots: x[a*192 + 4r+64u + j] * Wl_d[i][4r+64u + j] ----
        float s0[4] = {0,0,0,0}, s1[4] = {0,0,0,0};
        #pragma unroll
        for (int u = 0; u < 3; ++u) {
            const float4 xa = A0[u];
            const float4 xb = A1[u];
            #pragma unroll
            for (int i = 0; i < 4; ++i) {
                const float4 lv = *(const float4*)&sLd[i*192 + 4*r + 64*u];
                s0[i] = fmaf(xa.x, lv.x, s0[i]);  s1[i] = fmaf(xb.x, lv.x, s1[i]);
                s0[i] = fmaf(xa.y, lv.y, s0[i]);  s1[i] = fmaf(xb.y, lv.y, s1[i]);
                s0[i] = fmaf(xa.z, lv.z, s0[i]);  s1[i] = fmaf(xb.z, lv.z, s1[i]);
                s0[i] = fmaf(xa.w, lv.w, s0[i]);  s1[i] = fmaf(xb.w, lv.w, s1[i]);
            }
        }

        // ---- 16-lane DPP reduce + xor-swizzle gather + rule contraction ----
        float tD0[4], tD1[4];
        #pragma unroll
        for (int i = 0; i < 4; ++i) {
            const float rk0 = sRuleD[i*16 + (a^0)*4 + a];   // broadcast reads
            const float rk1 = sRuleD[i*16 + (a^1)*4 + a];
            const float rk2 = sRuleD[i*16 + (a^2)*4 + a];
            const float rk3 = sRuleD[i*16 + (a^3)*4 + a];
            const float h0 = reduce16(s0[i]);
            const float h1 = reduce16(s1[i]);
            float x1 = __shfl_xor(h0, 16), x2 = __shfl_xor(h0, 32), x3 = __shfl_xor(x1, 32);
            tD0[i] = fmaf(h0, rk0, fmaf(x1, rk1, fmaf(x2, rk2, x3 * rk3)));
            x1 = __shfl_xor(h1, 16); x2 = __shfl_xor(h1, 32); x3 = __shfl_xor(x1, 32);
            tD1[i] = fmaf(h1, rk0, fmaf(x1, rk1, fmaf(x2, rk2, x3 * rk3)));
        }

        // ---- z + gelu at o = a*48 + 3r + w (mapping unchanged) ----
        float g0[3], g1[3];
        #pragma unroll
        for (int w = 0; w < 3; ++w) {
            float z0 = bd[w], z1 = bd[w];
            #pragma unroll
            for (int i = 0; i < 4; ++i) {
                z0 = fmaf(tD0[i], rdw[i][w], z0);
                z1 = fmaf(tD1[i], rdw[i][w], z1);
            }
            const float i0 = SQ2PI * fmaf(0.044715f*z0, z0*z0, z0);
            const float i1 = SQ2PI * fmaf(0.044715f*z1, z1*z1, z1);
            const float e0 = __expf(2.0f*i0);                // tanh(y)=1-2/(e^{2y}+1)
            const float e1 = __expf(2.0f*i1);
            g0[w] = 0.5f*z0*(1.0f + (1.0f - 2.0f/(e0 + 1.0f)));
            g1[w] = 0.5f*z1*(1.0f + (1.0f - 2.0f/(e1 + 1.0f)));
        }

        // ---- up dots + reduce + gather + rule contraction ----
        float tU0[4], tU1[4];
        #pragma unroll
        for (int i = 0; i < 4; ++i) {
            const float l0 = sLu[i*48 + 3*r + 0];
            const float l1 = sLu[i*48 + 3*r + 1];
            const float l2 = sLu[i*48 + 3*r + 2];
            const float rk0 = sRuleU[i*16 + (a^0)*4 + a];
            const float rk1 = sRuleU[i*16 + (a^1)*4 + a];
            const float rk2 = sRuleU[i*16 + (a^2)*4 + a];
            const float rk3 = sRuleU[i*16 + (a^3)*4 + a];
            float a0 = g0[0]*l0 + g0[1]*l1 + g0[2]*l2;
            float a1 = g1[0]*l0 + g1[1]*l1 + g1[2]*l2;
            const float h0 = reduce16(a0);
            const float h1 = reduce16(a1);
            float x1 = __shfl_xor(h0, 16), x2 = __shfl_xor(h0, 32), x3 = __shfl_xor(x1, 32);
            tU0[i] = fmaf(h0, rk0, fmaf(x1, rk1, fmaf(x2, rk2, x3 * rk3)));
            x1 = __shfl_xor(h1, 16); x2 = __shfl_xor(h1, 32); x3 = __shfl_xor(x1, 32);
            tU1[i] = fmaf(h1, rk0, fmaf(x1, rk1, fmaf(x2, rk2, x3 * rk3)));
        }

        // ---- outputs: coalesced nt stores (tU is row-broadcast, so lane
        //      writes the q2-slice 4r+64u of its block -> 256B/row segments)
        float* op = out + (size_t)pr * 1536 + off;
        #pragma unroll
        for (int u = 0; u < 3; ++u) {
            float4 ov0 = bu[u], ov1 = bu[u];
            #pragma unroll
            for (int i = 0; i < 4; ++i) {
                const float4 ru = *(const float4*)&sRu[i*192 + 4*r + 64*u];
                ov0.x = fmaf(tU0[i], ru.x, ov0.x);  ov1.x = fmaf(tU1[i], ru.x, ov1.x);
                ov0.y = fmaf(tU0[i], ru.y, ov0.y);  ov1.y = fmaf(tU1[i], ru.y, ov1.y);
                ov0.z = fmaf(tU0[i], ru.z, ov0.z);  ov1.z = fmaf(tU1[i], ru.z, ov1.z);
                ov0.w = fmaf(tU0[i], ru.w, ov0.w);  ov1.w = fmaf(tU1[i], ru.w, ov1.w);
            }
            nt_store4(op + 64*u,       ov0);
            nt_store4(op + 768 + 64*u, ov1);
        }

        // ---- rotate prefetch into current ----
        #pragma unroll
        for (int u = 0; u < 3; ++u) { A0[u] = B0[u]; A1[u] = B1[u]; }
    }
}

extern "C" void kernel_launch(void* const* d_in, const int* in_sizes, int n_in,
                              void* d_out, int out_size, void* d_ws, size_t ws_size,
                              hipStream_t stream) {
    const float* x      = (const float*)d_in[0];
    const float* rule_d = (const float*)d_in[1];
    const float* Wl_d   = (const float*)d_in[2];
    const float* Wr_d   = (const float*)d_in[3];
    const float* bias_d = (const float*)d_in[4];
    const float* rule_u = (const float*)d_in[5];
    const float* Wl_u   = (const float*)d_in[6];
    const float* Wr_u   = (const float*)d_in[7];
    const float* bias_u = (const float*)d_in[8];
    float* out          = (float*)d_out;

    const int n_tokens = in_sizes[0] / 768;   // 32768

    // 1024 blocks = 4096 waves; 16384 pairs -> exactly 4 pairs/wave, balanced.
    phm_fused<<<dim3(1024), dim3(256), 0, stream>>>(
        x, rule_d, Wl_d, Wr_d, bias_d, rule_u, Wl_u, Wr_u, bias_u, out, n_tokens);
}